// Round 7
// baseline (77.005 us; speedup 1.0000x reference)
//
#include <hip/hip_runtime.h>
#include <math.h>

#define NW 1e-5f
#define PI_SQRT 1.7724538509055159f
#define TWO_SQRT 1.4142135623730951f
#define SQRT_LOG2E 1.2011224087864498f   // sqrt(log2(e))
#define NT 128      // threads per eval block
#define PT 8        // field points per thread
#define TN (NT*PT)  // field points per tile (1024)
#define CB 64       // params per eval-block chunk

#if __has_builtin(__builtin_amdgcn_exp2f)
#define FAST_EXP2(x) __builtin_amdgcn_exp2f(x)
#else
#define FAST_EXP2(x) exp2f(x)
#endif

// ---------------------------------------------------------------------------
// Kernel A: one thread per (b,m). Computes params ONCE into dense d_ws array:
//   params[b*M+m] = {bc = bmean*c_s, c_s = c*sqrt(log2e), coef_s, 0}
// so eval does ua = fma(-f, c_s, bc). Also zeroes d_out (poisoned by harness).
// ---------------------------------------------------------------------------
__global__ __launch_bounds__(256) void param_kernel(
    const float* __restrict__ rf,      // [B, M, 3]
    const float* __restrict__ width,   // [B, M]
    const float* __restrict__ A_mean,  // [B, M]
    const float* __restrict__ area,    // [M]
    const float* __restrict__ sf,      // [B, N]
    float4* __restrict__ params,       // [B*M]
    float* __restrict__ out,           // [B*N]
    int B, int M, int N, int out_total) {

    const int idx = blockIdx.x * 256 + (int)threadIdx.x;
    if (idx < out_total) out[idx] = 0.0f;
    if (idx >= B * M) return;
    int b = idx / M;
    int m = idx - b * M;

    float r0 = rf[idx * 3 + 0];
    float r1 = rf[idx * 3 + 1];
    float r2 = rf[idx * 3 + 2];
    // exact descending 3-sort via min/max network
    float lo = fminf(r0, r1), hi = fmaxf(r0, r1);
    float B1 = fmaxf(hi, r2);
    float B3 = fminf(lo, r2);
    float B2 = fmaxf(lo, fminf(hi, r2));

    float w = width[idx];
    w = (w > NW) ? w : (w + NW);
    float inv_w = 1.0f / w;
    float d13 = (B1 - B3) * inv_w;
    float d23 = (B2 - B3) * inv_w;
    float d12 = (B1 - B2) * inv_w;
    float add_w_sq = (d13 * d13 + d23 * d23 + d12 * d12) * (1.0f / 9.0f);
    w = (w > 2.0f * NW) ? w : (w + 2.0f * NW);

    float f0   = sf[b * N];
    float step = sf[b * N + 1] - f0;
    float sw   = step * 0.5f;

    float ew = sqrtf(w * w * (1.0f + add_w_sq) + sw * sw);
    ew = (ew < sw * 0.5f) ? ew : (ew + sw * 0.5f);

    float bmean = (B1 + B2 + B3) * (1.0f / 3.0f);
    float c = TWO_SQRT / ew;
    float coef = 2.0f * A_mean[idx] * area[m] * c * c / PI_SQRT;

    float c_s    = c * SQRT_LOG2E;
    float coef_s = coef / SQRT_LOG2E;
    params[idx] = make_float4(bmean * c_s, c_s, coef_s, 0.0f);
}

// ---------------------------------------------------------------------------
// Kernel B: block = (tile, chunk, b). Stages its CB-param chunk into LDS,
// then each thread evaluates PT=8 field points over the chunk — one
// ds_read_b128 amortized over 8 pair-evals (round 6 was LDS-pipe-bound at
// PT=2). Per pair: fma, mul(-ua*ua), exp2, mul, fmac. No cutoff mask
// (tail <= 1.2e-4*coef; measured absmax 0.25 vs 0.855 threshold).
// ---------------------------------------------------------------------------
__global__ __launch_bounds__(NT) void eval_kernel(
    const float4* __restrict__ params, // [B*M]
    const float* __restrict__ sf,      // [B, N]
    float* __restrict__ out,           // [B, N] (pre-zeroed by param_kernel)
    int M, int N) {

    const int b    = blockIdx.z;
    const int tile = blockIdx.x;
    const int tid  = (int)threadIdx.x;

    __shared__ float4 sp[CB];
    {
        int g = blockIdx.y * CB + tid;
        if (tid < CB)
            sp[tid] = (g < M) ? params[(size_t)b * M + g]
                              : make_float4(0.f, 0.f, 0.f, 0.f);
    }

    // this thread's PT field points (coalesced: stride NT)
    float f[PT];
    int   n[PT];
    const float f0 = sf[b * N];
    #pragma unroll
    for (int j = 0; j < PT; ++j) {
        n[j] = tile * TN + j * NT + tid;
        f[j] = (n[j] < N) ? sf[b * N + n[j]] : f0;
    }

    __syncthreads();

    float acc[PT];
    #pragma unroll
    for (int j = 0; j < PT; ++j) acc[j] = 0.0f;

    #pragma unroll 2
    for (int i = 0; i < CB; ++i) {
        float4 q = sp[i];
        #pragma unroll
        for (int j = 0; j < PT; ++j) {
            float ua = __builtin_fmaf(-f[j], q.y, q.x);  // (bmean - f)*c_s
            float e  = FAST_EXP2(-(ua * ua));
            acc[j] += (q.z * ua) * e;
        }
    }

    #pragma unroll
    for (int j = 0; j < PT; ++j)
        if (n[j] < N) atomicAdd(&out[b * N + n[j]], acc[j]);
}

extern "C" void kernel_launch(void* const* d_in, const int* in_sizes, int n_in,
                              void* d_out, int out_size, void* d_ws, size_t ws_size,
                              hipStream_t stream) {
    const float* rf     = (const float*)d_in[0];  // [B, M, 3]
    const float* width  = (const float*)d_in[1];  // [B, M]
    const float* A_mean = (const float*)d_in[2];  // [B, M]
    const float* area   = (const float*)d_in[3];  // [M]
    const float* sf     = (const float*)d_in[4];  // [B, N]

    const int M  = in_sizes[3];
    const int BM = in_sizes[1];
    const int B  = BM / M;
    const int N  = in_sizes[4] / B;

    float* out     = (float*)d_out;
    float4* params = (float4*)d_ws;   // B*M float4s

    param_kernel<<<(BM + 255) / 256, 256, 0, stream>>>(
        rf, width, A_mean, area, sf, params, out, B, M, N, out_size);

    const int ntiles = (N + TN - 1) / TN;
    const int chunks = (M + CB - 1) / CB;
    dim3 grid(ntiles, chunks, B);
    eval_kernel<<<grid, NT, 0, stream>>>(params, sf, out, M, N);
}

// Round 8
// 74.916 us; speedup vs baseline: 1.0279x; 1.0279x over previous
//
#include <hip/hip_runtime.h>
#include <math.h>

#define NW 1e-5f
#define PI_SQRT 1.7724538509055159f
#define TWO_SQRT 1.4142135623730951f
#define SQRT_LOG2E 1.2011224087864498f   // sqrt(log2(e))
#define NT 256      // threads per eval block
#define PT 4        // field points per thread
#define TN (NT*PT)  // field points per tile (1024)
#define CB 128      // params per eval-block chunk

#if __has_builtin(__builtin_amdgcn_exp2f)
#define FAST_EXP2(x) __builtin_amdgcn_exp2f(x)
#else
#define FAST_EXP2(x) exp2f(x)
#endif

// ---------------------------------------------------------------------------
// Kernel A: one thread per (b,m). Computes params ONCE into dense d_ws array:
//   params[b*M+m] = {bc = bmean*c_s, c_s = c*sqrt(log2e), coef_s, 0}
// so eval does ua = fma(-f, c_s, bc). Also zeroes d_out (poisoned by harness).
// ---------------------------------------------------------------------------
__global__ __launch_bounds__(256) void param_kernel(
    const float* __restrict__ rf,      // [B, M, 3]
    const float* __restrict__ width,   // [B, M]
    const float* __restrict__ A_mean,  // [B, M]
    const float* __restrict__ area,    // [M]
    const float* __restrict__ sf,      // [B, N]
    float4* __restrict__ params,       // [B*M]
    float* __restrict__ out,           // [B*N]
    int B, int M, int N, int out_total) {

    const int idx = blockIdx.x * 256 + (int)threadIdx.x;
    if (idx < out_total) out[idx] = 0.0f;
    if (idx >= B * M) return;
    int b = idx / M;
    int m = idx - b * M;

    float r0 = rf[idx * 3 + 0];
    float r1 = rf[idx * 3 + 1];
    float r2 = rf[idx * 3 + 2];
    // exact descending 3-sort via min/max network
    float lo = fminf(r0, r1), hi = fmaxf(r0, r1);
    float B1 = fmaxf(hi, r2);
    float B3 = fminf(lo, r2);
    float B2 = fmaxf(lo, fminf(hi, r2));

    float w = width[idx];
    w = (w > NW) ? w : (w + NW);
    float inv_w = 1.0f / w;
    float d13 = (B1 - B3) * inv_w;
    float d23 = (B2 - B3) * inv_w;
    float d12 = (B1 - B2) * inv_w;
    float add_w_sq = (d13 * d13 + d23 * d23 + d12 * d12) * (1.0f / 9.0f);
    w = (w > 2.0f * NW) ? w : (w + 2.0f * NW);

    float f0   = sf[b * N];
    float step = sf[b * N + 1] - f0;
    float sw   = step * 0.5f;

    float ew = sqrtf(w * w * (1.0f + add_w_sq) + sw * sw);
    ew = (ew < sw * 0.5f) ? ew : (ew + sw * 0.5f);

    float bmean = (B1 + B2 + B3) * (1.0f / 3.0f);
    float c = TWO_SQRT / ew;
    float coef = 2.0f * A_mean[idx] * area[m] * c * c / PI_SQRT;

    float c_s    = c * SQRT_LOG2E;
    float coef_s = coef / SQRT_LOG2E;
    params[idx] = make_float4(bmean * c_s, c_s, coef_s, 0.0f);
}

// ---------------------------------------------------------------------------
// Kernel B: block = (tile, chunk, b). Stages its CB-param chunk into LDS,
// each thread evaluates PT=4 field points over the chunk.
// Config rationale (R6/R7 post-mortems): 2048 waves (8/CU, 2/SIMD) so one
// wave's v_exp_f32 drain overlaps the other's VALU; PT=4 gives 4 independent
// chains (enough ILP) without R7's 1M-atomic tail (512K here, 64/address).
// Per pair: fma, mul(neg), exp2, mul, fmac — no cutoff mask (absmax 0.25
// measured vs 0.855 threshold).
// ---------------------------------------------------------------------------
__global__ __launch_bounds__(NT) void eval_kernel(
    const float4* __restrict__ params, // [B*M]
    const float* __restrict__ sf,      // [B, N]
    float* __restrict__ out,           // [B, N] (pre-zeroed by param_kernel)
    int M, int N) {

    const int b    = blockIdx.z;
    const int tile = blockIdx.x;
    const int tid  = (int)threadIdx.x;

    __shared__ float4 sp[CB];
    {
        int g = blockIdx.y * CB + tid;
        if (tid < CB)
            sp[tid] = (g < M) ? params[(size_t)b * M + g]
                              : make_float4(0.f, 0.f, 0.f, 0.f);
    }

    // this thread's PT field points (coalesced: stride NT)
    float f[PT];
    int   n[PT];
    const float f0 = sf[b * N];
    #pragma unroll
    for (int j = 0; j < PT; ++j) {
        n[j] = tile * TN + j * NT + tid;
        f[j] = (n[j] < N) ? sf[b * N + n[j]] : f0;
    }

    __syncthreads();

    float acc[PT];
    #pragma unroll
    for (int j = 0; j < PT; ++j) acc[j] = 0.0f;

    #pragma unroll 4
    for (int i = 0; i < CB; ++i) {
        float4 q = sp[i];
        #pragma unroll
        for (int j = 0; j < PT; ++j) {
            float ua = __builtin_fmaf(-f[j], q.y, q.x);  // (bmean - f)*c_s
            float e  = FAST_EXP2(-(ua * ua));
            acc[j] += (q.z * ua) * e;
        }
    }

    #pragma unroll
    for (int j = 0; j < PT; ++j)
        if (n[j] < N) atomicAdd(&out[b * N + n[j]], acc[j]);
}

extern "C" void kernel_launch(void* const* d_in, const int* in_sizes, int n_in,
                              void* d_out, int out_size, void* d_ws, size_t ws_size,
                              hipStream_t stream) {
    const float* rf     = (const float*)d_in[0];  // [B, M, 3]
    const float* width  = (const float*)d_in[1];  // [B, M]
    const float* A_mean = (const float*)d_in[2];  // [B, M]
    const float* area   = (const float*)d_in[3];  // [M]
    const float* sf     = (const float*)d_in[4];  // [B, N]

    const int M  = in_sizes[3];
    const int BM = in_sizes[1];
    const int B  = BM / M;
    const int N  = in_sizes[4] / B;

    float* out     = (float*)d_out;
    float4* params = (float4*)d_ws;   // B*M float4s

    param_kernel<<<(BM + 255) / 256, 256, 0, stream>>>(
        rf, width, A_mean, area, sf, params, out, B, M, N, out_size);

    const int ntiles = (N + TN - 1) / TN;
    const int chunks = (M + CB - 1) / CB;
    dim3 grid(ntiles, chunks, B);
    eval_kernel<<<grid, NT, 0, stream>>>(params, sf, out, M, N);
}